// Round 11
// baseline (139.801 us; speedup 1.0000x reference)
//
#include <hip/hip_runtime.h>
#include <hip/hip_bf16.h>
#include <stdint.h>

#define B_ 8
#define C_ 512
#define N_ 2048

typedef __bf16 bf16_t;
typedef bf16_t bf16x8 __attribute__((ext_vector_type(8)));
typedef bf16_t bf16x4 __attribute__((ext_vector_type(4)));
typedef float f32x4 __attribute__((ext_vector_type(4)));

// ---------------------------------------------------------------------------
// weights_kernel (1 dispatch, 195 blocks):
//   0..63    WqT[i][c] = wq[c][i]   (bf16)
//   64..127  WkT[i][c] = wk[c][i]   (bf16)
//   128..191 Wvb = cast(wv)         (bf16)
//   192      gk[i] = sum_c wk[c,i]*bq[c]   (fp32)
//   193      va[i] = sum_c wq[c,i]*bk[c]   (fp32)
//   194      s1 = bk.bq                    (fp32 scalar)
// Vec blocks read fp32 inputs directly -> no intra-dispatch hazard.
// ---------------------------------------------------------------------------
__global__ __launch_bounds__(256) void weights_kernel(
    const float* __restrict__ wq, const float* __restrict__ wk,
    const float* __restrict__ wv, const float* __restrict__ bq,
    const float* __restrict__ bk,
    bf16_t* __restrict__ WqT, bf16_t* __restrict__ WkT,
    bf16_t* __restrict__ Wvb, float* __restrict__ gk,
    float* __restrict__ va, float* __restrict__ s1p)
{
    __shared__ bf16_t tile[64][65];
    __shared__ float fl[512];
    __shared__ float red[256];
    const int t = blockIdx.x;
    const int tid = threadIdx.x;
    if (t < 128) {
        const float* src = (t < 64) ? wq : wk;
        bf16_t* dst = (t < 64) ? WqT : WkT;
        const int j = t & 63;
        const int i0 = (j & 7) * 64, c0 = (j >> 3) * 64;
        const int cx = (tid & 15) * 4, ry = tid >> 4;
#pragma unroll
        for (int r = ry; r < 64; r += 16) {
            float4 f = *(const float4*)&src[(size_t)(c0 + r) * C_ + i0 + cx];
            tile[r][cx + 0] = (bf16_t)f.x; tile[r][cx + 1] = (bf16_t)f.y;
            tile[r][cx + 2] = (bf16_t)f.z; tile[r][cx + 3] = (bf16_t)f.w;
        }
        __syncthreads();
#pragma unroll
        for (int r = ry; r < 64; r += 16) {
            bf16x4 o;
            o[0] = tile[cx + 0][r]; o[1] = tile[cx + 1][r];
            o[2] = tile[cx + 2][r]; o[3] = tile[cx + 3][r];
            *(bf16x4*)&dst[(size_t)(i0 + r) * C_ + c0 + cx] = o;
        }
    } else if (t < 192) {
        const int j = t - 128;
#pragma unroll
        for (int p = 0; p < 4; ++p) {
            const int i = j * 4096 + p * 1024 + tid * 4;
            float4 f = *(const float4*)(wv + i);
            bf16x4 o;
            o[0] = (bf16_t)f.x; o[1] = (bf16_t)f.y;
            o[2] = (bf16_t)f.z; o[3] = (bf16_t)f.w;
            *(bf16x4*)(Wvb + i) = o;
        }
    } else if (t < 194) {
        const float* W = (t == 192) ? wk : wq;
        const float* bb = (t == 192) ? bq : bk;
        float* out = (t == 192) ? gk : va;
        fl[tid] = bb[tid]; fl[tid + 256] = bb[tid + 256];
        __syncthreads();
        float a0 = 0.f, a1 = 0.f;
#pragma unroll 4
        for (int c1 = 0; c1 < C_; ++c1) {
            float2 ww = *(const float2*)&W[(size_t)c1 * C_ + 2 * tid];
            a0 += ww.x * fl[c1];
            a1 += ww.y * fl[c1];
        }
        out[2 * tid] = a0;
        out[2 * tid + 1] = a1;
    } else {
        float p = bk[tid] * bq[tid] + bk[tid + 256] * bq[tid + 256];
        red[tid] = p;
        __syncthreads();
        for (int s = 128; s > 0; s >>= 1) {
            if (tid < s) red[tid] += red[tid + s];
            __syncthreads();
        }
        if (tid == 0) s1p[0] = red[0];
    }
}

// ---------------------------------------------------------------------------
// prep_q: q fp32 [B][C][N] -> qT bf16 [B][N][C]  AND  qc bf16 [B][C][N].
// ---------------------------------------------------------------------------
__global__ __launch_bounds__(256) void prep_q_kernel(
    const float* __restrict__ q, bf16_t* __restrict__ qT, bf16_t* __restrict__ qc)
{
    __shared__ bf16_t tile[64][65];
    const int b = blockIdx.z;
    const float* src = q + (size_t)b * C_ * N_;
    bf16_t* dT = qT + (size_t)b * N_ * C_;
    bf16_t* dc = qc + (size_t)b * C_ * N_;
    const int n0 = blockIdx.x * 64, c0 = blockIdx.y * 64;
    const int t = threadIdx.x;
    const int cx = (t & 15) * 4, ry = t >> 4;
#pragma unroll
    for (int r = ry; r < 64; r += 16) {
        float4 f = *(const float4*)&src[(size_t)(c0 + r) * N_ + n0 + cx];
        bf16x4 o;
        o[0] = (bf16_t)f.x; o[1] = (bf16_t)f.y;
        o[2] = (bf16_t)f.z; o[3] = (bf16_t)f.w;
        tile[r][cx + 0] = o[0]; tile[r][cx + 1] = o[1];
        tile[r][cx + 2] = o[2]; tile[r][cx + 3] = o[3];
        *(bf16x4*)&dc[(size_t)(c0 + r) * N_ + n0 + cx] = o;
    }
    __syncthreads();
#pragma unroll
    for (int r = ry; r < 64; r += 16) {
        bf16x4 o;
        o[0] = tile[cx + 0][r]; o[1] = tile[cx + 1][r];
        o[2] = tile[cx + 2][r]; o[3] = tile[cx + 3][r];
        *(bf16x4*)&dT[(size_t)(n0 + r) * C_ + c0 + cx] = o;
    }
}

// ---------------------------------------------------------------------------
// gemm_dkv (r9-proven, 39.7 us): Dp[b*4+sp][i,j] = sum_{n in sp} k[i,n]v[j,n].
// fp32 inputs via global_load_lds, BK=64 (2x32 KB LDS), split-K 4, 512 blocks,
// 2-barrier sync, chunk swizzle slot = c ^ (r&7). sk4/sv4 per-split row sums.
// ---------------------------------------------------------------------------
__global__ __launch_bounds__(256) void gemm_dkv(
    const float* __restrict__ Kin, const float* __restrict__ Vin,
    bf16_t* __restrict__ Dp, float* __restrict__ sk4, float* __restrict__ sv4)
{
    __shared__ __align__(16) float As[128 * 64];   // 32 KB
    __shared__ __align__(16) float Bs[128 * 64];   // 32 KB

    const int f = blockIdx.x;
    const int xcd = f & 7, sl = f >> 3;
    const int g = xcd + 8 * (sl >> 4), t5 = sl & 15;   // g in [0,32)
    const int bz = g >> 2, sp = g & 3;
    const int m0 = (t5 >> 2) * 128, n0 = (t5 & 3) * 128;
    const int kbeg = sp * 512;

    const int tid = threadIdx.x, lane = tid & 63, wave = tid >> 6;
    const int wr = wave >> 1, wc = wave & 1;

    const float* Ab = Kin + (size_t)bz * C_ * N_;
    const float* Bb = Vin + (size_t)bz * C_ * N_;

    f32x4 acc[4][4];
#pragma unroll
    for (int i = 0; i < 4; ++i)
#pragma unroll
        for (int j = 0; j < 4; ++j) acc[i][j] = 0.f;

    const int prow = tid >> 4;                      // 0..15
    const int cs   = (tid & 15) ^ (prow & 7);
    const int ldso = tid * 16;

    const int srr = tid >> 1, hh = tid & 1;
    float hsA = 0.f, hsB = 0.f;
    const bool doA = (n0 == 0), doB = (m0 == 0);

    for (int t = 0; t < 8; ++t) {
        const float* ga = Ab + (size_t)(m0 + prow) * N_ + kbeg + t * 64 + cs * 4;
        const float* gb = Bb + (size_t)(n0 + prow) * N_ + kbeg + t * 64 + cs * 4;
#pragma unroll
        for (int p = 0; p < 8; ++p)
            __builtin_amdgcn_global_load_lds(
                (const __attribute__((address_space(1))) void*)(ga + (size_t)p * 16 * N_),
                (__attribute__((address_space(3))) void*)((char*)As + ldso + p * 4096),
                16, 0, 0);
#pragma unroll
        for (int p = 0; p < 8; ++p)
            __builtin_amdgcn_global_load_lds(
                (const __attribute__((address_space(1))) void*)(gb + (size_t)p * 16 * N_),
                (__attribute__((address_space(3))) void*)((char*)Bs + ldso + p * 4096),
                16, 0, 0);
        __syncthreads();

#pragma unroll
        for (int kk = 0; kk < 64; kk += 32) {
            bf16x8 af[4], bfr[4];
            const int kcol = kk + (lane >> 4) * 8;
            const int c1 = kcol >> 2;
#pragma unroll
            for (int m = 0; m < 4; ++m) {
                const int r = wr * 64 + (lane & 15) + m * 16;
                f32x4 lo = *(const f32x4*)((const char*)As + r * 256 + ((c1 ^ (r & 7)) << 4));
                f32x4 hi = *(const f32x4*)((const char*)As + r * 256 + (((c1 + 1) ^ (r & 7)) << 4));
                bf16x8 fr;
                fr[0] = (bf16_t)lo[0]; fr[1] = (bf16_t)lo[1];
                fr[2] = (bf16_t)lo[2]; fr[3] = (bf16_t)lo[3];
                fr[4] = (bf16_t)hi[0]; fr[5] = (bf16_t)hi[1];
                fr[6] = (bf16_t)hi[2]; fr[7] = (bf16_t)hi[3];
                af[m] = fr;
            }
#pragma unroll
            for (int n = 0; n < 4; ++n) {
                const int r = wc * 64 + (lane & 15) + n * 16;
                f32x4 lo = *(const f32x4*)((const char*)Bs + r * 256 + ((c1 ^ (r & 7)) << 4));
                f32x4 hi = *(const f32x4*)((const char*)Bs + r * 256 + (((c1 + 1) ^ (r & 7)) << 4));
                bf16x8 fr;
                fr[0] = (bf16_t)lo[0]; fr[1] = (bf16_t)lo[1];
                fr[2] = (bf16_t)lo[2]; fr[3] = (bf16_t)lo[3];
                fr[4] = (bf16_t)hi[0]; fr[5] = (bf16_t)hi[1];
                fr[6] = (bf16_t)hi[2]; fr[7] = (bf16_t)hi[3];
                bfr[n] = fr;
            }
#pragma unroll
            for (int m = 0; m < 4; ++m)
#pragma unroll
                for (int n = 0; n < 4; ++n)
                    acc[m][n] = __builtin_amdgcn_mfma_f32_16x16x32_bf16(
                        af[m], bfr[n], acc[m][n], 0, 0, 0);
        }

        if (doA) {
#pragma unroll
            for (int u = 0; u < 8; ++u) {
                const int slot = ((hh * 8 + u) + srr) & 15;
                f32x4 vv = *(const f32x4*)((const char*)As + srr * 256 + slot * 16);
                hsA += vv[0] + vv[1] + vv[2] + vv[3];
            }
        }
        if (doB) {
#pragma unroll
            for (int u = 0; u < 8; ++u) {
                const int slot = ((hh * 8 + u) + srr) & 15;
                f32x4 vv = *(const f32x4*)((const char*)Bs + srr * 256 + slot * 16);
                hsB += vv[0] + vv[1] + vv[2] + vv[3];
            }
        }
        __syncthreads();
    }

    const int rj = (lane >> 4) * 4;
    const int cc = lane & 15;
    const size_t sCC = (size_t)C_ * C_;
    const int z = bz * 4 + sp;
#pragma unroll
    for (int m = 0; m < 4; ++m) {
#pragma unroll
        for (int n = 0; n < 4; ++n) {
            const int col = n0 + wc * 64 + n * 16 + cc;
            f32x4 vv = acc[m][n];
#pragma unroll
            for (int j = 0; j < 4; ++j) {
                const int row = m0 + wr * 64 + m * 16 + rj + j;
                Dp[(size_t)z * sCC + (size_t)row * C_ + col] = (bf16_t)vv[j];
            }
        }
    }
    if (doA) {
        hsA += __shfl_xor(hsA, 1, 64);
        if (!hh) sk4[(size_t)(sp * B_ + bz) * C_ + m0 + srr] = hsA;
    }
    if (doB) {
        hsB += __shfl_xor(hsB, 1, 64);
        if (!hh) sv4[(size_t)(sp * B_ + bz) * C_ + n0 + srr] = hsB;
    }
}

// ---------------------------------------------------------------------------
// reduce_mv: blocks 0..1023: D = sum of 4 split partials.
//   1024..1031: u[b] = Wv . (sum_sp sv4)
//   1032..1039: vbraw[b] = M . sk[b];  s2[b] = sk[b].gk + N*s1
// ---------------------------------------------------------------------------
__global__ __launch_bounds__(256) void reduce_mv_kernel(
    const bf16_t* __restrict__ Pt, bf16_t* __restrict__ Out,
    const bf16_t* __restrict__ Wvb, const bf16_t* __restrict__ M,
    const float* __restrict__ sk4, const float* __restrict__ sv4,
    const float* __restrict__ gk, const float* __restrict__ s1p,
    float* __restrict__ u, float* __restrict__ vbraw, float* __restrict__ s2)
{
    __shared__ float svec[C_];
    __shared__ float red[256];
    const size_t sCC = (size_t)C_ * C_;
    const int bid = blockIdx.x, tid = threadIdx.x;
    if (bid < 1024) {
        size_t idx = ((size_t)bid * 256 + tid) * 8;
        size_t b = idx / sCC;
        size_t r = idx - b * sCC;
        const bf16_t* base = Pt + (b * 4) * sCC + r;
        float acc[8];
#pragma unroll
        for (int j = 0; j < 8; ++j) acc[j] = 0.f;
#pragma unroll
        for (int s = 0; s < 4; ++s) {
            bf16x8 pv = *(const bf16x8*)(base + (size_t)s * sCC);
#pragma unroll
            for (int j = 0; j < 8; ++j) acc[j] += (float)pv[j];
        }
        bf16x8 o;
#pragma unroll
        for (int j = 0; j < 8; ++j) o[j] = (bf16_t)acc[j];
        *(bf16x8*)(Out + idx) = o;
    } else if (bid < 1032) {
        const int b = bid - 1024;
        const float* s4 = sv4 + (size_t)b * C_;
        const size_t st = (size_t)B_ * C_;
#pragma unroll
        for (int rr = 0; rr < 2; ++rr) {
            const int j = tid * 2 + rr;
            svec[j] = s4[j] + s4[st + j] + s4[2 * st + j] + s4[3 * st + j];
        }
        __syncthreads();
        const int c = tid * 2;
#pragma unroll
        for (int rr = 0; rr < 2; ++rr) {
            const bf16_t* row = Wvb + (size_t)(c + rr) * C_;
            float acc = 0.f;
            for (int j = 0; j < C_; j += 8) {
                bf16x8 vv = *(const bf16x8*)(row + j);
#pragma unroll
                for (int e = 0; e < 8; ++e) acc += (float)vv[e] * svec[j + e];
            }
            u[b * C_ + c + rr] = acc;
        }
    } else {
        const int b = bid - 1032;
        const float* s4 = sk4 + (size_t)b * C_;
        const size_t st = (size_t)B_ * C_;
#pragma unroll
        for (int rr = 0; rr < 2; ++rr) {
            const int j = tid * 2 + rr;
            svec[j] = s4[j] + s4[st + j] + s4[2 * st + j] + s4[3 * st + j];
        }
        __syncthreads();
        const int c = tid * 2;
#pragma unroll
        for (int rr = 0; rr < 2; ++rr) {
            const bf16_t* row = M + (size_t)(c + rr) * C_;
            float acc = 0.f;
            for (int j = 0; j < C_; j += 8) {
                bf16x8 vv = *(const bf16x8*)(row + j);
#pragma unroll
                for (int e = 0; e < 8; ++e) acc += (float)vv[e] * svec[j + e];
            }
            vbraw[b * C_ + c + rr] = acc;
        }
        float p = svec[tid] * gk[tid] + svec[tid + 256] * gk[tid + 256];
        red[tid] = p;
        __syncthreads();
        for (int s = 128; s > 0; s >>= 1) {
            if (tid < s) red[tid] += red[tid + s];
            __syncthreads();
        }
        if (tid == 0) s2[b] = red[0] + 2048.0f * s1p[0];
    }
}

// ---------------------------------------------------------------------------
// 64x64-tile NT bf16 GEMM. K = 512 fixed.
// EPI 0: plain bf16 out.
// EPI 3 (HT): val += e0[bz*C+row]*e1[col] + e2[row]*(e3[bz*C+col] + 2048*e1[col]);
//             x==0 blocks also compute h: hout[bz*C+row'] =
//             sum_col A[row',col]*bqv[col] + e0[bz*C+row']*s1 + e2[row']*s2[bz].
// ---------------------------------------------------------------------------
template <int EPI>
__global__ __launch_bounds__(256) void gemm64_nt(
    const bf16_t* __restrict__ A, const bf16_t* __restrict__ Bm,
    bf16_t* __restrict__ Cout, size_t sA, size_t sB, size_t sC,
    const float* __restrict__ e0, const float* __restrict__ e1,
    const float* __restrict__ e2, const float* __restrict__ e3,
    const float* __restrict__ bqv, float* __restrict__ hout,
    const float* __restrict__ s1p, const float* __restrict__ s2p)
{
    __shared__ __align__(16) bf16_t As[64 * 64];   // 8 KB
    __shared__ __align__(16) bf16_t Bs[64 * 64];

    const int tid = threadIdx.x, lane = tid & 63, wave = tid >> 6;
    const int wr = wave >> 1, wc = wave & 1;
    const int bz = blockIdx.z;
    const int m0 = blockIdx.y * 64, n0 = blockIdx.x * 64;
    const int K = C_;

    const bf16_t* Ab = A + (size_t)bz * sA;
    const bf16_t* Bb = Bm + (size_t)bz * sB;

    f32x4 acc[2][2];
#pragma unroll
    for (int i = 0; i < 2; ++i)
#pragma unroll
        for (int j = 0; j < 2; ++j) acc[i][j] = 0.f;

    const int srow = tid >> 3;
    const int scol = ((tid & 7) ^ (srow & 7)) * 8;
    const int ldso = tid * 16;

    float hacc = 0.f;
    const bool doH = (EPI == 3) && (blockIdx.x == 0);

    for (int t = 0; t < 8; ++t) {
        const bf16_t* ga = Ab + (size_t)(m0 + srow) * K + t * 64 + scol;
        const bf16_t* gb = Bb + (size_t)(n0 + srow) * K + t * 64 + scol;
#pragma unroll
        for (int p = 0; p < 2; ++p)
            __builtin_amdgcn_global_load_lds(
                (const __attribute__((address_space(1))) void*)(ga + (size_t)p * 32 * K),
                (__attribute__((address_space(3))) void*)((char*)As + ldso + p * 4096),
                16, 0, 0);
#pragma unroll
        for (int p = 0; p < 2; ++p)
            __builtin_amdgcn_global_load_lds(
                (const __attribute__((address_space(1))) void*)(gb + (size_t)p * 32 * K),
                (__attribute__((address_space(3))) void*)((char*)Bs + ldso + p * 4096),
                16, 0, 0);
        __syncthreads();

#pragma unroll
        for (int kk = 0; kk < 64; kk += 32) {
            bf16x8 af[2], bfr[2];
            const int kcol = kk + (lane >> 4) * 8;
            const int kc = kcol >> 3;
#pragma unroll
            for (int m = 0; m < 2; ++m) {
                const int r = wr * 32 + (lane & 15) + m * 16;
                af[m] = *(const bf16x8*)((const char*)As + r * 128 +
                                         ((kc ^ (r & 7)) << 4));
            }
#pragma unroll
            for (int n = 0; n < 2; ++n) {
                const int r = wc * 32 + (lane & 15) + n * 16;
                bfr[n] = *(const bf16x8*)((const char*)Bs + r * 128 +
                                          ((kc ^ (r & 7)) << 4));
            }
#pragma unroll
            for (int m = 0; m < 2; ++m)
#pragma unroll
                for (int n = 0; n < 2; ++n)
                    acc[m][n] = __builtin_amdgcn_mfma_f32_16x16x32_bf16(
                        af[m], bfr[n], acc[m][n], 0, 0, 0);
        }
        if (doH) {
            const int rr = tid >> 2, qq = tid & 3;
#pragma unroll
            for (int u = 0; u < 2; ++u) {
                const int c = qq * 2 + u;
                bf16x8 av = *(const bf16x8*)((const char*)As + rr * 128 +
                                             ((c ^ (rr & 7)) << 4));
                const float* bp = bqv + t * 64 + c * 8;
#pragma unroll
                for (int e = 0; e < 8; ++e) hacc += (float)av[e] * bp[e];
            }
        }
        __syncthreads();
    }

    const int rj = (lane >> 4) * 4;
    const int cc = lane & 15;
#pragma unroll
    for (int m = 0; m < 2; ++m) {
#pragma unroll
        for (int n = 0; n < 2; ++n) {
            const int col = n0 + wc * 32 + n * 16 + cc;
            f32x4 vv = acc[m][n];
#pragma unroll
            for (int j = 0; j < 4; ++j) {
                const int row = m0 + wr * 32 + m * 16 + rj + j;
                float val = vv[j];
                if (EPI == 3)
                    val += e0[bz * C_ + row] * e1[col] +
                           e2[row] * (e3[bz * C_ + col] + 2048.0f * e1[col]);
                Cout[(size_t)bz * sC + (size_t)row * C_ + col] = (bf16_t)val;
            }
        }
    }
    if (doH) {
        hacc += __shfl_xor(hacc, 1, 64);
        hacc += __shfl_xor(hacc, 2, 64);
        if ((tid & 3) == 0) {
            const int row = m0 + (tid >> 2);
            hout[bz * C_ + row] = hacc + e0[bz * C_ + row] * s1p[0] +
                                  e2[row] * s2p[bz];
        }
    }
}

// ---------------------------------------------------------------------------
// Final GEMM: out[c,n] = sum_i HT[c,i]*qT[n,i] + h[b][c] + (float)qc[c,n].
// 1-D swizzled grid (512).
// ---------------------------------------------------------------------------
__global__ __launch_bounds__(256) void gemm_final(
    const bf16_t* __restrict__ A, const bf16_t* __restrict__ Bm,
    float* __restrict__ Cout, const bf16_t* __restrict__ qc,
    const float* __restrict__ hvec)
{
    __shared__ __align__(16) bf16_t As[128 * 64];
    __shared__ __align__(16) bf16_t Bs[128 * 64];

    const int f = blockIdx.x;
    const int xcd = f & 7, sl = f >> 3;
    const int g = xcd + 8 * (sl >> 2);
    const int m0 = (sl & 3) * 128;
    const int bz = g >> 4;
    const int n0 = (g & 15) * 128;
    const int K = C_;

    const int tid = threadIdx.x, lane = tid & 63, wave = tid >> 6;
    const int wr = wave >> 1, wc = wave & 1;

    const bf16_t* Ab = A + (size_t)bz * ((size_t)C_ * C_);
    const bf16_t* Bb = Bm + (size_t)bz * ((size_t)N_ * C_);

    f32x4 acc[4][4];
#pragma unroll
    for (int i = 0; i < 4; ++i)
#pragma unroll
        for (int j = 0; j < 4; ++j) acc[i][j] = 0.f;

    const int srow = tid >> 3;
    const int scol = ((tid & 7) ^ (srow & 7)) * 8;
    const int ldso = tid * 16;

    for (int t = 0; t < 8; ++t) {
        const bf16_t* ga = Ab + (size_t)(m0 + srow) * K + t * 64 + scol;
        const bf16_t* gb = Bb + (size_t)(n0 + srow) * K + t * 64 + scol;
#pragma unroll
        for (int p = 0; p < 4; ++p)
            __builtin_amdgcn_global_load_lds(
                (const __attribute__((address_space(1))) void*)(ga + (size_t)p * 32 * K),
                (__attribute__((address_space(3))) void*)((char*)As + ldso + p * 4096),
                16, 0, 0);
#pragma unroll
        for (int p = 0; p < 4; ++p)
            __builtin_amdgcn_global_load_lds(
                (const __attribute__((address_space(1))) void*)(gb + (size_t)p * 32 * K),
                (__attribute__((address_space(3))) void*)((char*)Bs + ldso + p * 4096),
                16, 0, 0);
        __syncthreads();

#pragma unroll
        for (int kk = 0; kk < 64; kk += 32) {
            bf16x8 af[4], bfr[4];
            const int kcol = kk + (lane >> 4) * 8;
            const int kc = kcol >> 3;
#pragma unroll
            for (int m = 0; m < 4; ++m) {
                const int r = wr * 64 + (lane & 15) + m * 16;
                af[m] = *(const bf16x8*)((const char*)As + r * 128 +
                                         ((kc ^ (r & 7)) << 4));
            }
#pragma unroll
            for (int n = 0; n < 4; ++n) {
                const int r = wc * 64 + (lane & 15) + n * 16;
                bfr[n] = *(const bf16x8*)((const char*)Bs + r * 128 +
                                          ((kc ^ (r & 7)) << 4));
            }
#pragma unroll
            for (int m = 0; m < 4; ++m)
#pragma unroll
                for (int n = 0; n < 4; ++n)
                    acc[m][n] = __builtin_amdgcn_mfma_f32_16x16x32_bf16(
                        af[m], bfr[n], acc[m][n], 0, 0, 0);
        }
        __syncthreads();
    }

    const int rj = (lane >> 4) * 4;
    const int cc = lane & 15;
    const size_t ob = (size_t)bz * ((size_t)C_ * N_);
#pragma unroll
    for (int m = 0; m < 4; ++m) {
#pragma unroll
        for (int n = 0; n < 4; ++n) {
            const int col = n0 + wc * 64 + n * 16 + cc;
            f32x4 vv = acc[m][n];
#pragma unroll
            for (int j = 0; j < 4; ++j) {
                const int row = m0 + wr * 64 + m * 16 + rj + j;
                const size_t o = ob + (size_t)row * N_ + col;
                Cout[o] = vv[j] + hvec[bz * C_ + row] + (float)qc[o];
            }
        }
    }
}

// ---------------------------------------------------------------------------
extern "C" void kernel_launch(void* const* d_in, const int* in_sizes, int n_in,
                              void* d_out, int out_size, void* d_ws, size_t ws_size,
                              hipStream_t stream)
{
    (void)in_sizes; (void)n_in; (void)out_size; (void)ws_size;
    const float* q  = (const float*)d_in[0];
    const float* k  = (const float*)d_in[1];
    const float* v  = (const float*)d_in[2];
    const float* wq = (const float*)d_in[3];
    const float* bq = (const float*)d_in[4];
    const float* wk = (const float*)d_in[5];
    const float* bk = (const float*)d_in[6];
    const float* wv = (const float*)d_in[7];
    const float* bv = (const float*)d_in[8];
    float* out = (float*)d_out;

    char* ws = (char*)d_ws;
    const size_t WSZ = (size_t)C_ * C_ * 2;            // 512 KB
    const size_t TSZ = (size_t)B_ * N_ * C_ * 2;       // 16.78 MB
    const size_t SCZ = (size_t)B_ * C_ * C_ * 2;       // 4.19 MB
    const size_t VSZ = (size_t)B_ * C_ * 4;            // 16 KB
    const size_t sCC = (size_t)C_ * C_;
    size_t off = 0;
    bf16_t* WqTb = (bf16_t*)(ws + off); off += WSZ;
    bf16_t* WkTb = (bf16_t*)(ws + off); off += WSZ;
    bf16_t* Wvb  = (bf16_t*)(ws + off); off += WSZ;
    bf16_t* M    = (bf16_t*)(ws + off); off += WSZ;
    bf16_t* qT   = (bf16_t*)(ws + off); off += TSZ;
    bf16_t* qc   = (bf16_t*)(ws + off); off += TSZ;
    bf16_t* Dp   = (bf16_t*)(ws + off); off += TSZ;    // 32 x sCC partials
    bf16_t* D    = (bf16_t*)(ws + off); off += SCZ;
    bf16_t* P1   = (bf16_t*)(ws + off); off += SCZ;
    bf16_t* HT   = (bf16_t*)(ws + off); off += SCZ;
    float*  sk4  = (float*)(ws + off);  off += 4 * VSZ;
    float*  sv4  = (float*)(ws + off);  off += 4 * VSZ;
    float*  gk   = (float*)(ws + off);  off += C_ * 4;
    float*  va   = (float*)(ws + off);  off += C_ * 4;
    float*  s1p  = (float*)(ws + off);  off += 64;
    float*  s2   = (float*)(ws + off);  off += 64;
    float*  uu   = (float*)(ws + off);  off += VSZ;
    float*  vbr  = (float*)(ws + off);  off += VSZ;
    float*  hb   = (float*)(ws + off);  off += VSZ;

    const dim3 blk(256);

    // 1. weights: WqT, WkT, Wv cast + gk, va, s1 (weight-only vectors)
    weights_kernel<<<dim3(195), blk, 0, stream>>>(
        wq, wk, wv, bq, bk, WqTb, WkTb, Wvb, gk, va, s1p);

    // 2. M[i',i] = sum_c wq[c,i'] wk[c,i]  (batch-independent, 64 blocks)
    gemm64_nt<0><<<dim3(8, 8, 1), blk, 0, stream>>>(
        WqTb, WkTb, M, 0, 0, 0,
        nullptr, nullptr, nullptr, nullptr, nullptr, nullptr, nullptr, nullptr);

    // 3. q -> qT (bf16 [B,N,C]) + qc (bf16 [B,C,N])
    prep_q_kernel<<<dim3(N_ / 64, C_ / 64, B_), blk, 0, stream>>>(q, qT, qc);

    // 4. D partials from fp32 k,v (split-K 4, BK=64 — r9 config) + sk4/sv4
    gemm_dkv<<<dim3(512), blk, 0, stream>>>(k, v, Dp, sk4, sv4);

    // 5. reduce Dp -> D;  u = Wv.sv;  vbraw = M.sk;  s2 = sk.gk + N*s1
    reduce_mv_kernel<<<dim3(1040), blk, 0, stream>>>(
        Dp, D, Wvb, M, sk4, sv4, gk, s1p, uu, vbr, s2);

    // 6. P1[c2,i] = sum_j Wv[c2,j] D[i,j]
    gemm64_nt<0><<<dim3(8, 8, B_), blk, 0, stream>>>(
        Wvb, D, P1, 0, sCC, sCC,
        nullptr, nullptr, nullptr, nullptr, nullptr, nullptr, nullptr, nullptr);

    // 7. HT = P1.M^T + u (x) va + bv (x) (vbraw + N*va);  h folded (x==0)
    gemm64_nt<3><<<dim3(8, 8, B_), blk, 0, stream>>>(
        P1, M, HT, sCC, 0, sCC, uu, va, bv, vbr, gk, hb, s1p, s2);

    // 8. out = HT.qT^T + h + qc   (fp32, final layout, XCD-swizzled)
    gemm_final<<<dim3(512), blk, 0, stream>>>(HT, qT, out, qc, hb);
}

// Round 12
// 118.711 us; speedup vs baseline: 1.1777x; 1.1777x over previous
//
#include <hip/hip_runtime.h>
#include <hip/hip_bf16.h>
#include <stdint.h>

#define B_ 8
#define C_ 512
#define N_ 2048

typedef __bf16 bf16_t;
typedef bf16_t bf16x8 __attribute__((ext_vector_type(8)));
typedef bf16_t bf16x4 __attribute__((ext_vector_type(4)));
typedef float f32x4 __attribute__((ext_vector_type(4)));

// ---------------------------------------------------------------------------
// weights_kernel (193 blocks):
//   0..63    WqT[i][c] = wq[c][i]   (bf16)
//   64..127  WkT[i][c] = wk[c][i]   (bf16)
//   128..191 Wvb = cast(wv)         (bf16)
//   192      s1 = bk.bq             (fp32 scalar)
// ---------------------------------------------------------------------------
__global__ __launch_bounds__(256) void weights_kernel(
    const float* __restrict__ wq, const float* __restrict__ wk,
    const float* __restrict__ wv, const float* __restrict__ bq,
    const float* __restrict__ bk,
    bf16_t* __restrict__ WqT, bf16_t* __restrict__ WkT,
    bf16_t* __restrict__ Wvb, float* __restrict__ s1p)
{
    __shared__ bf16_t tile[64][65];
    __shared__ float red[256];
    const int t = blockIdx.x;
    const int tid = threadIdx.x;
    if (t < 128) {
        const float* src = (t < 64) ? wq : wk;
        bf16_t* dst = (t < 64) ? WqT : WkT;
        const int j = t & 63;
        const int i0 = (j & 7) * 64, c0 = (j >> 3) * 64;
        const int cx = (tid & 15) * 4, ry = tid >> 4;
#pragma unroll
        for (int r = ry; r < 64; r += 16) {
            float4 f = *(const float4*)&src[(size_t)(c0 + r) * C_ + i0 + cx];
            tile[r][cx + 0] = (bf16_t)f.x; tile[r][cx + 1] = (bf16_t)f.y;
            tile[r][cx + 2] = (bf16_t)f.z; tile[r][cx + 3] = (bf16_t)f.w;
        }
        __syncthreads();
#pragma unroll
        for (int r = ry; r < 64; r += 16) {
            bf16x4 o;
            o[0] = tile[cx + 0][r]; o[1] = tile[cx + 1][r];
            o[2] = tile[cx + 2][r]; o[3] = tile[cx + 3][r];
            *(bf16x4*)&dst[(size_t)(i0 + r) * C_ + c0 + cx] = o;
        }
    } else if (t < 192) {
        const int j = t - 128;
#pragma unroll
        for (int p = 0; p < 4; ++p) {
            const int i = j * 4096 + p * 1024 + tid * 4;
            float4 f = *(const float4*)(wv + i);
            bf16x4 o;
            o[0] = (bf16_t)f.x; o[1] = (bf16_t)f.y;
            o[2] = (bf16_t)f.z; o[3] = (bf16_t)f.w;
            *(bf16x4*)(Wvb + i) = o;
        }
    } else {
        float p = bk[tid] * bq[tid] + bk[tid + 256] * bq[tid + 256];
        red[tid] = p;
        __syncthreads();
        for (int s = 128; s > 0; s >>= 1) {
            if (tid < s) red[tid] += red[tid + s];
            __syncthreads();
        }
        if (tid == 0) s1p[0] = red[0];
    }
}

// ---------------------------------------------------------------------------
// gemm_M_aux (80 blocks): 0..63 compute M[i',i] = sum_c WqT[i',c]*WkT[i,c]
// (64x64 tiles, r8-proven body); 64..71: gk = WkT.bq; 72..79: va = WqT.bk
// (parallel row-dots: 4 threads/row, contiguous bf16x8).
// ---------------------------------------------------------------------------
__global__ __launch_bounds__(256) void gemm_M_aux(
    const bf16_t* __restrict__ WqT, const bf16_t* __restrict__ WkT,
    bf16_t* __restrict__ M, const float* __restrict__ bq,
    const float* __restrict__ bk, float* __restrict__ gk,
    float* __restrict__ va)
{
    __shared__ __align__(16) bf16_t As[64 * 64];
    __shared__ __align__(16) bf16_t Bs[64 * 64];
    const int tid = threadIdx.x;
    if (blockIdx.x < 64) {
        const int lane = tid & 63, wave = tid >> 6;
        const int wr = wave >> 1, wc = wave & 1;
        const int m0 = (blockIdx.x >> 3) * 64, n0 = (blockIdx.x & 7) * 64;
        const int K = C_;
        f32x4 acc[2][2];
#pragma unroll
        for (int i = 0; i < 2; ++i)
#pragma unroll
            for (int j = 0; j < 2; ++j) acc[i][j] = 0.f;
        const int srow = tid >> 3;
        const int scol = ((tid & 7) ^ (srow & 7)) * 8;
        const int ldso = tid * 16;
        for (int t = 0; t < 8; ++t) {
            const bf16_t* ga = WqT + (size_t)(m0 + srow) * K + t * 64 + scol;
            const bf16_t* gb = WkT + (size_t)(n0 + srow) * K + t * 64 + scol;
#pragma unroll
            for (int p = 0; p < 2; ++p)
                __builtin_amdgcn_global_load_lds(
                    (const __attribute__((address_space(1))) void*)(ga + (size_t)p * 32 * K),
                    (__attribute__((address_space(3))) void*)((char*)As + ldso + p * 4096),
                    16, 0, 0);
#pragma unroll
            for (int p = 0; p < 2; ++p)
                __builtin_amdgcn_global_load_lds(
                    (const __attribute__((address_space(1))) void*)(gb + (size_t)p * 32 * K),
                    (__attribute__((address_space(3))) void*)((char*)Bs + ldso + p * 4096),
                    16, 0, 0);
            __syncthreads();
#pragma unroll
            for (int kk = 0; kk < 64; kk += 32) {
                bf16x8 af[2], bfr[2];
                const int kcol = kk + (lane >> 4) * 8;
                const int kc = kcol >> 3;
#pragma unroll
                for (int m = 0; m < 2; ++m) {
                    const int r = wr * 32 + (lane & 15) + m * 16;
                    af[m] = *(const bf16x8*)((const char*)As + r * 128 +
                                             ((kc ^ (r & 7)) << 4));
                }
#pragma unroll
                for (int n = 0; n < 2; ++n) {
                    const int r = wc * 32 + (lane & 15) + n * 16;
                    bfr[n] = *(const bf16x8*)((const char*)Bs + r * 128 +
                                              ((kc ^ (r & 7)) << 4));
                }
#pragma unroll
                for (int m = 0; m < 2; ++m)
#pragma unroll
                    for (int n = 0; n < 2; ++n)
                        acc[m][n] = __builtin_amdgcn_mfma_f32_16x16x32_bf16(
                            af[m], bfr[n], acc[m][n], 0, 0, 0);
            }
            __syncthreads();
        }
        const int rj = (lane >> 4) * 4;
        const int cc = lane & 15;
#pragma unroll
        for (int m = 0; m < 2; ++m)
#pragma unroll
            for (int n = 0; n < 2; ++n) {
                const int col = n0 + wc * 32 + n * 16 + cc;
                f32x4 vv = acc[m][n];
#pragma unroll
                for (int j = 0; j < 4; ++j) {
                    const int row = m0 + wr * 32 + m * 16 + rj + j;
                    M[(size_t)row * C_ + col] = (bf16_t)vv[j];
                }
            }
    } else {
        const int j = (int)blockIdx.x - 64;            // 0..15
        const bf16_t* W = (j < 8) ? WkT : WqT;
        const float* bb = (j < 8) ? bq : bk;
        float* out = (j < 8) ? gk : va;
        const int row = (j & 7) * 64 + (tid >> 2);
        const int c0 = (tid & 3) * 128;
        const bf16_t* rp = W + (size_t)row * C_ + c0;
        float acc = 0.f;
#pragma unroll
        for (int e = 0; e < 128; e += 8) {
            bf16x8 vv = *(const bf16x8*)(rp + e);
#pragma unroll
            for (int x = 0; x < 8; ++x) acc += (float)vv[x] * bb[c0 + e + x];
        }
        acc += __shfl_xor(acc, 1, 64);
        acc += __shfl_xor(acc, 2, 64);
        if ((tid & 3) == 0) out[row] = acc;
    }
}

// ---------------------------------------------------------------------------
// prep (10240 blocks): 0..8191 cast k,v rows -> bf16 + row sums (r8-proven);
// 8192..10239 transpose-cast q -> qT + qc (r1/r9-proven).
// ---------------------------------------------------------------------------
__global__ __launch_bounds__(256) void prep_kernel(
    const float* __restrict__ kin, const float* __restrict__ vin,
    const float* __restrict__ q,
    bf16_t* __restrict__ kc, bf16_t* __restrict__ vc,
    bf16_t* __restrict__ qT, bf16_t* __restrict__ qc,
    float* __restrict__ sk, float* __restrict__ sv)
{
    __shared__ bf16_t tile[64][65];
    __shared__ float red[4];
    const int bid = blockIdx.x;
    const int tid = threadIdx.x;
    if (bid < 8192) {
        const int row = bid & 4095;            // b*C + c
        const int selv = bid >> 12;
        const float* src = (selv ? vin : kin) + (size_t)row * N_;
        bf16_t* dst = (selv ? vc : kc) + (size_t)row * N_;
        const int i = tid * 8;
        float4 f0 = *(const float4*)(src + i);
        float4 f1 = *(const float4*)(src + i + 4);
        bf16x8 o;
        o[0] = (bf16_t)f0.x; o[1] = (bf16_t)f0.y; o[2] = (bf16_t)f0.z; o[3] = (bf16_t)f0.w;
        o[4] = (bf16_t)f1.x; o[5] = (bf16_t)f1.y; o[6] = (bf16_t)f1.z; o[7] = (bf16_t)f1.w;
        *(bf16x8*)(dst + i) = o;
        float s = f0.x + f0.y + f0.z + f0.w + f1.x + f1.y + f1.z + f1.w;
#pragma unroll
        for (int d = 1; d < 64; d <<= 1) s += __shfl_xor(s, d, 64);
        if ((tid & 63) == 0) red[tid >> 6] = s;
        __syncthreads();
        if (tid == 0)
            (selv ? sv : sk)[row] = red[0] + red[1] + red[2] + red[3];
    } else {
        const int t = bid - 8192;
        const int b = t >> 8;
        const int rem = t & 255;
        const int c0 = (rem >> 5) * 64;
        const int n0 = (rem & 31) * 64;
        const float* src = q + (size_t)b * C_ * N_;
        bf16_t* dT = qT + (size_t)b * N_ * C_;
        bf16_t* dc = qc + (size_t)b * C_ * N_;
        const int cx = (tid & 15) * 4, ry = tid >> 4;
#pragma unroll
        for (int r = ry; r < 64; r += 16) {
            float4 f = *(const float4*)&src[(size_t)(c0 + r) * N_ + n0 + cx];
            bf16x4 o;
            o[0] = (bf16_t)f.x; o[1] = (bf16_t)f.y;
            o[2] = (bf16_t)f.z; o[3] = (bf16_t)f.w;
            tile[r][cx + 0] = o[0]; tile[r][cx + 1] = o[1];
            tile[r][cx + 2] = o[2]; tile[r][cx + 3] = o[3];
            *(bf16x4*)&dc[(size_t)(c0 + r) * N_ + n0 + cx] = o;
        }
        __syncthreads();
#pragma unroll
        for (int r = ry; r < 64; r += 16) {
            bf16x4 o;
            o[0] = tile[cx + 0][r]; o[1] = tile[cx + 1][r];
            o[2] = tile[cx + 2][r]; o[3] = tile[cx + 3][r];
            *(bf16x4*)&dT[(size_t)(n0 + r) * C_ + c0 + cx] = o;
        }
    }
}

// ---------------------------------------------------------------------------
// Split-K NT bf16 GEMM (r2/r8-proven): C[m,n] = sum_k A[m,k]*B[n,k], bf16 out.
// Single-buffer, 2 barriers/K-step, global_load_lds both sides with source
// chunk pre-swizzle + swizzled conflict-free reads. blockIdx.z = b*SPLITS+sp.
// ---------------------------------------------------------------------------
template <int SPLITS>
__global__ __launch_bounds__(256, 2) void gemm_ntK(
    const bf16_t* __restrict__ A, const bf16_t* __restrict__ Bm,
    bf16_t* __restrict__ Cout,
    int Nn, int K, size_t sA, size_t sB, size_t sC)
{
    __shared__ __align__(16) bf16_t As[128 * 64];
    __shared__ __align__(16) bf16_t Bs[128 * 64];

    const int tid = threadIdx.x, lane = tid & 63, wave = tid >> 6;
    const int wr = wave >> 1, wc = wave & 1;
    const int bz = blockIdx.z / SPLITS;
    const int sp = blockIdx.z % SPLITS;
    const int kbeg = sp * (K / SPLITS);
    const int nt = (K / SPLITS) / 64;

    const bf16_t* Ab = A + (size_t)bz * sA;
    const bf16_t* Bb = Bm + (size_t)bz * sB;
    const int m0 = blockIdx.y * 128, n0 = blockIdx.x * 128;

    f32x4 acc[4][4];
#pragma unroll
    for (int i = 0; i < 4; ++i)
#pragma unroll
        for (int j = 0; j < 4; ++j) acc[i][j] = 0.f;

    const int srow = tid >> 3;
    const int scol = ((tid & 7) ^ (srow & 7)) * 8;
    const int ldso = tid * 16;

    for (int t = 0; t < nt; ++t) {
        const bf16_t* ga = Ab + (size_t)(m0 + srow) * K + kbeg + t * 64 + scol;
        const bf16_t* gb = Bb + (size_t)(n0 + srow) * K + kbeg + t * 64 + scol;
#pragma unroll
        for (int p = 0; p < 4; ++p)
            __builtin_amdgcn_global_load_lds(
                (const __attribute__((address_space(1))) void*)(ga + (size_t)p * 32 * K),
                (__attribute__((address_space(3))) void*)((char*)As + ldso + p * 4096),
                16, 0, 0);
#pragma unroll
        for (int p = 0; p < 4; ++p)
            __builtin_amdgcn_global_load_lds(
                (const __attribute__((address_space(1))) void*)(gb + (size_t)p * 32 * K),
                (__attribute__((address_space(3))) void*)((char*)Bs + ldso + p * 4096),
                16, 0, 0);
        __syncthreads();

#pragma unroll
        for (int kk = 0; kk < 64; kk += 32) {
            bf16x8 af[4], bfr[4];
            const int kcol = kk + (lane >> 4) * 8;
            const int kc = kcol >> 3;
#pragma unroll
            for (int m = 0; m < 4; ++m) {
                const int r = wr * 64 + (lane & 15) + m * 16;
                af[m] = *(const bf16x8*)((const char*)As + r * 128 +
                                         ((kc ^ (r & 7)) << 4));
            }
#pragma unroll
            for (int n = 0; n < 4; ++n) {
                const int r = wc * 64 + (lane & 15) + n * 16;
                bfr[n] = *(const bf16x8*)((const char*)Bs + r * 128 +
                                          ((kc ^ (r & 7)) << 4));
            }
#pragma unroll
            for (int m = 0; m < 4; ++m)
#pragma unroll
                for (int n = 0; n < 4; ++n)
                    acc[m][n] = __builtin_amdgcn_mfma_f32_16x16x32_bf16(
                        af[m], bfr[n], acc[m][n], 0, 0, 0);
        }
        __syncthreads();
    }

    const int rj = (lane >> 4) * 4;
    const int cc = lane & 15;
#pragma unroll
    for (int m = 0; m < 4; ++m) {
#pragma unroll
        for (int n = 0; n < 4; ++n) {
            const int col = n0 + wc * 64 + n * 16 + cc;
            f32x4 vv = acc[m][n];
#pragma unroll
            for (int j = 0; j < 4; ++j) {
                const int row = m0 + wr * 64 + m * 16 + rj + j;
                Cout[(size_t)blockIdx.z * sC + (size_t)row * Nn + col] = (bf16_t)vv[j];
            }
        }
    }
}

// ---------------------------------------------------------------------------
// reduce_mv: blocks 0..1023: D = sum of 4 split partials.
//   1024..1031: u[b] = Wv . sv[b]
//   1032..1039: vbraw[b] = M . sk[b];  s2[b] = sk[b].gk + N*s1
// ---------------------------------------------------------------------------
__global__ __launch_bounds__(256) void reduce_mv_kernel(
    const bf16_t* __restrict__ Pt, bf16_t* __restrict__ Out,
    const bf16_t* __restrict__ Wvb, const bf16_t* __restrict__ M,
    const float* __restrict__ sk, const float* __restrict__ sv,
    const float* __restrict__ gk, const float* __restrict__ s1p,
    float* __restrict__ u, float* __restrict__ vbraw, float* __restrict__ s2)
{
    __shared__ float svec[C_];
    __shared__ float red[256];
    const size_t sCC = (size_t)C_ * C_;
    const int bid = blockIdx.x, tid = threadIdx.x;
    if (bid < 1024) {
        size_t idx = ((size_t)bid * 256 + tid) * 8;
        size_t b = idx / sCC;
        size_t r = idx - b * sCC;
        const bf16_t* base = Pt + (b * 4) * sCC + r;
        float acc[8];
#pragma unroll
        for (int j = 0; j < 8; ++j) acc[j] = 0.f;
#pragma unroll
        for (int s = 0; s < 4; ++s) {
            bf16x8 pv = *(const bf16x8*)(base + (size_t)s * sCC);
#pragma unroll
            for (int j = 0; j < 8; ++j) acc[j] += (float)pv[j];
        }
        bf16x8 o;
#pragma unroll
        for (int j = 0; j < 8; ++j) o[j] = (bf16_t)acc[j];
        *(bf16x8*)(Out + idx) = o;
    } else if (bid < 1032) {
        const int b = bid - 1024;
        const float* s4 = sv + (size_t)b * C_;
#pragma unroll
        for (int rr = 0; rr < 2; ++rr) {
            const int j = tid * 2 + rr;
            svec[j] = s4[j];
        }
        __syncthreads();
        const int c = tid * 2;
#pragma unroll
        for (int rr = 0; rr < 2; ++rr) {
            const bf16_t* row = Wvb + (size_t)(c + rr) * C_;
            float acc = 0.f;
            for (int j = 0; j < C_; j += 8) {
                bf16x8 vv = *(const bf16x8*)(row + j);
#pragma unroll
                for (int e = 0; e < 8; ++e) acc += (float)vv[e] * svec[j + e];
            }
            u[b * C_ + c + rr] = acc;
        }
    } else {
        const int b = bid - 1032;
        const float* s4 = sk + (size_t)b * C_;
#pragma unroll
        for (int rr = 0; rr < 2; ++rr) {
            const int j = tid * 2 + rr;
            svec[j] = s4[j];
        }
        __syncthreads();
        const int c = tid * 2;
#pragma unroll
        for (int rr = 0; rr < 2; ++rr) {
            const bf16_t* row = M + (size_t)(c + rr) * C_;
            float acc = 0.f;
            for (int j = 0; j < C_; j += 8) {
                bf16x8 vv = *(const bf16x8*)(row + j);
#pragma unroll
                for (int e = 0; e < 8; ++e) acc += (float)vv[e] * svec[j + e];
            }
            vbraw[b * C_ + c + rr] = acc;
        }
        float p = svec[tid] * gk[tid] + svec[tid + 256] * gk[tid + 256];
        red[tid] = p;
        __syncthreads();
        for (int s = 128; s > 0; s >>= 1) {
            if (tid < s) red[tid] += red[tid + s];
            __syncthreads();
        }
        if (tid == 0) s2[b] = red[0] + 2048.0f * s1p[0];
    }
}

// ---------------------------------------------------------------------------
// 64x64-tile NT bf16 GEMM. K = 512 fixed.
// EPI 0: plain bf16 out.
// EPI 3 (HT): val += e0[bz*C+row]*e1[col] + e2[row]*(e3[bz*C+col] + 2048*e1[col]);
//             x==0 blocks also compute h (folded, r11-verified).
// ---------------------------------------------------------------------------
template <int EPI>
__global__ __launch_bounds__(256) void gemm64_nt(
    const bf16_t* __restrict__ A, const bf16_t* __restrict__ Bm,
    bf16_t* __restrict__ Cout, size_t sA, size_t sB, size_t sC,
    const float* __restrict__ e0, const float* __restrict__ e1,
    const float* __restrict__ e2, const float* __restrict__ e3,
    const float* __restrict__ bqv, float* __restrict__ hout,
    const float* __restrict__ s1p, const float* __restrict__ s2p)
{
    __shared__ __align__(16) bf16_t As[64 * 64];
    __shared__ __align__(16) bf16_t Bs[64 * 64];

    const int tid = threadIdx.x, lane = tid & 63, wave = tid >> 6;
    const int wr = wave >> 1, wc = wave & 1;
    const int bz = blockIdx.z;
    const int m0 = blockIdx.y * 64, n0 = blockIdx.x * 64;
    const int K = C_;

    const bf16_t* Ab = A + (size_t)bz * sA;
    const bf16_t* Bb = Bm + (size_t)bz * sB;

    f32x4 acc[2][2];
#pragma unroll
    for (int i = 0; i < 2; ++i)
#pragma unroll
        for (int j = 0; j < 2; ++j) acc[i][j] = 0.f;

    const int srow = tid >> 3;
    const int scol = ((tid & 7) ^ (srow & 7)) * 8;
    const int ldso = tid * 16;

    float hacc = 0.f;
    const bool doH = (EPI == 3) && (blockIdx.x == 0);

    for (int t = 0; t < 8; ++t) {
        const bf16_t* ga = Ab + (size_t)(m0 + srow) * K + t * 64 + scol;
        const bf16_t* gb = Bb + (size_t)(n0 + srow) * K + t * 64 + scol;
#pragma unroll
        for (int p = 0; p < 2; ++p)
            __builtin_amdgcn_global_load_lds(
                (const __attribute__((address_space(1))) void*)(ga + (size_t)p * 32 * K),
                (__attribute__((address_space(3))) void*)((char*)As + ldso + p * 4096),
                16, 0, 0);
#pragma unroll
        for (int p = 0; p < 2; ++p)
            __builtin_amdgcn_global_load_lds(
                (const __attribute__((address_space(1))) void*)(gb + (size_t)p * 32 * K),
                (__attribute__((address_space(3))) void*)((char*)Bs + ldso + p * 4096),
                16, 0, 0);
        __syncthreads();

#pragma unroll
        for (int kk = 0; kk < 64; kk += 32) {
            bf16x8 af[2], bfr[2];
            const int kcol = kk + (lane >> 4) * 8;
            const int kc = kcol >> 3;
#pragma unroll
            for (int m = 0; m < 2; ++m) {
                const int r = wr * 32 + (lane & 15) + m * 16;
                af[m] = *(const bf16x8*)((const char*)As + r * 128 +
                                         ((kc ^ (r & 7)) << 4));
            }
#pragma unroll
            for (int n = 0; n < 2; ++n) {
                const int r = wc * 32 + (lane & 15) + n * 16;
                bfr[n] = *(const bf16x8*)((const char*)Bs + r * 128 +
                                          ((kc ^ (r & 7)) << 4));
            }
#pragma unroll
            for (int m = 0; m < 2; ++m)
#pragma unroll
                for (int n = 0; n < 2; ++n)
                    acc[m][n] = __builtin_amdgcn_mfma_f32_16x16x32_bf16(
                        af[m], bfr[n], acc[m][n], 0, 0, 0);
        }
        if (doH) {
            const int rr = tid >> 2, qq = tid & 3;
#pragma unroll
            for (int u = 0; u < 2; ++u) {
                const int c = qq * 2 + u;
                bf16x8 av = *(const bf16x8*)((const char*)As + rr * 128 +
                                             ((c ^ (rr & 7)) << 4));
                const float* bp = bqv + t * 64 + c * 8;
#pragma unroll
                for (int e = 0; e < 8; ++e) hacc += (float)av[e] * bp[e];
            }
        }
        __syncthreads();
    }

    const int rj = (lane >> 4) * 4;
    const int cc = lane & 15;
#pragma unroll
    for (int m = 0; m < 2; ++m) {
#pragma unroll
        for (int n = 0; n < 2; ++n) {
            const int col = n0 + wc * 32 + n * 16 + cc;
            f32x4 vv = acc[m][n];
#pragma unroll
            for (int j = 0; j < 4; ++j) {
                const int row = m0 + wr * 32 + m * 16 + rj + j;
                float val = vv[j];
                if (EPI == 3)
                    val += e0[bz * C_ + row] * e1[col] +
                           e2[row] * (e3[bz * C_ + col] + 2048.0f * e1[col]);
                Cout[(size_t)bz * sC + (size_t)row * C_ + col] = (bf16_t)val;
            }
        }
    }
    if (doH) {
        hacc += __shfl_xor(hacc, 1, 64);
        hacc += __shfl_xor(hacc, 2, 64);
        if ((tid & 3) == 0) {
            const int row = m0 + (tid >> 2);
            hout[bz * C_ + row] = hacc + e0[bz * C_ + row] * s1p[0] +
                                  e2[row] * s2p[bz];
        }
    }
}

// ---------------------------------------------------------------------------
// Final GEMM: out[c,n] = sum_i HT[c,i]*qT[n,i] + h[b][c] + (float)qc[c,n].
// 1-D swizzled grid (512).
// ---------------------------------------------------------------------------
__global__ __launch_bounds__(256) void gemm_final(
    const bf16_t* __restrict__ A, const bf16_t* __restrict__ Bm,
    float* __restrict__ Cout, const bf16_t* __restrict__ qc,
    const float* __restrict__ hvec)
{
    __shared__ __align__(16) bf16_t As[128 * 64];
    __shared__ __align__(16) bf16_t Bs[128 * 64];

    const int f = blockIdx.x;
    const int xcd = f & 7, sl = f >> 3;
    const int g = xcd + 8 * (sl >> 2);
    const int m0 = (sl & 3) * 128;
    const int bz = g >> 4;
    const int n0 = (g & 15) * 128;
    const int K = C_;

    const int tid = threadIdx.x, lane = tid & 63, wave = tid >> 6;
    const int wr = wave >> 1, wc = wave & 1;

    const bf16_t* Ab = A + (size_t)bz * ((size_t)C_ * C_);
    const bf16_t* Bb = Bm + (size_t)bz * ((size_t)N_ * C_);

    f32x4 acc[4][4];
#pragma unroll
    for (int i = 0; i < 4; ++i)
#pragma unroll
        for (int j = 0; j < 4; ++j) acc[i][j] = 0.f;

    const int srow = tid >> 3;
    const int scol = ((tid & 7) ^ (srow & 7)) * 8;
    const int ldso = tid * 16;

    for (int t = 0; t < 8; ++t) {
        const bf16_t* ga = Ab + (size_t)(m0 + srow) * K + t * 64 + scol;
        const bf16_t* gb = Bb + (size_t)(n0 + srow) * K + t * 64 + scol;
#pragma unroll
        for (int p = 0; p < 4; ++p)
            __builtin_amdgcn_global_load_lds(
                (const __attribute__((address_space(1))) void*)(ga + (size_t)p * 32 * K),
                (__attribute__((address_space(3))) void*)((char*)As + ldso + p * 4096),
                16, 0, 0);
#pragma unroll
        for (int p = 0; p < 4; ++p)
            __builtin_amdgcn_global_load_lds(
                (const __attribute__((address_space(1))) void*)(gb + (size_t)p * 32 * K),
                (__attribute__((address_space(3))) void*)((char*)Bs + ldso + p * 4096),
                16, 0, 0);
        __syncthreads();

#pragma unroll
        for (int kk = 0; kk < 64; kk += 32) {
            bf16x8 af[4], bfr[4];
            const int kcol = kk + (lane >> 4) * 8;
            const int kc = kcol >> 3;
#pragma unroll
            for (int m = 0; m < 4; ++m) {
                const int r = wr * 64 + (lane & 15) + m * 16;
                af[m] = *(const bf16x8*)((const char*)As + r * 128 +
                                         ((kc ^ (r & 7)) << 4));
            }
#pragma unroll
            for (int n = 0; n < 4; ++n) {
                const int r = wc * 64 + (lane & 15) + n * 16;
                bfr[n] = *(const bf16x8*)((const char*)Bs + r * 128 +
                                          ((kc ^ (r & 7)) << 4));
            }
#pragma unroll
            for (int m = 0; m < 4; ++m)
#pragma unroll
                for (int n = 0; n < 4; ++n)
                    acc[m][n] = __builtin_amdgcn_mfma_f32_16x16x32_bf16(
                        af[m], bfr[n], acc[m][n], 0, 0, 0);
        }
        __syncthreads();
    }

    const int rj = (lane >> 4) * 4;
    const int cc = lane & 15;
    const size_t ob = (size_t)bz * ((size_t)C_ * N_);
#pragma unroll
    for (int m = 0; m < 4; ++m) {
#pragma unroll
        for (int n = 0; n < 4; ++n) {
            const int col = n0 + wc * 64 + n * 16 + cc;
            f32x4 vv = acc[m][n];
#pragma unroll
            for (int j = 0; j < 4; ++j) {
                const int row = m0 + wr * 64 + m * 16 + rj + j;
                const size_t o = ob + (size_t)row * N_ + col;
                Cout[o] = vv[j] + hvec[bz * C_ + row] + (float)qc[o];
            }
        }
    }
}

// ---------------------------------------------------------------------------
extern "C" void kernel_launch(void* const* d_in, const int* in_sizes, int n_in,
                              void* d_out, int out_size, void* d_ws, size_t ws_size,
                              hipStream_t stream)
{
    (void)in_sizes; (void)n_in; (void)out_size; (void)ws_size;
    const float* q  = (const float*)d_in[0];
    const float* k  = (const float*)d_in[1];
    const float* v  = (const float*)d_in[2];
    const float* wq = (const float*)d_in[3];
    const float* bq = (const float*)d_in[4];
    const float* wk = (const float*)d_in[5];
    const float* bk = (const float*)d_in[6];
    const float* wv = (const float*)d_in[7];
    const float* bv = (const float*)d_in[8];
    float* out = (float*)d_out;

    char* ws = (char*)d_ws;
    const size_t WSZ = (size_t)C_ * C_ * 2;            // 512 KB
    const size_t TSZ = (size_t)B_ * N_ * C_ * 2;       // 16.78 MB
    const size_t SCZ = (size_t)B_ * C_ * C_ * 2;       // 4.19 MB
    const size_t VSZ = (size_t)B_ * C_ * 4;            // 16 KB
    const size_t sCC = (size_t)C_ * C_;
    const size_t sBN = (size_t)N_ * C_;
    size_t off = 0;
    bf16_t* WqTb = (bf16_t*)(ws + off); off += WSZ;
    bf16_t* WkTb = (bf16_t*)(ws + off); off += WSZ;
    bf16_t* Wvb  = (bf16_t*)(ws + off); off += WSZ;
    bf16_t* M    = (bf16_t*)(ws + off); off += WSZ;
    bf16_t* qT   = (bf16_t*)(ws + off); off += TSZ;
    bf16_t* qc   = (bf16_t*)(ws + off); off += TSZ;
    bf16_t* kc   = (bf16_t*)(ws + off); off += TSZ;
    bf16_t* vc   = (bf16_t*)(ws + off); off += TSZ;
    bf16_t* Dp   = (bf16_t*)(ws + off); off += TSZ;    // 32 x sCC partials
    bf16_t* D    = (bf16_t*)(ws + off); off += SCZ;
    bf16_t* P1   = (bf16_t*)(ws + off); off += SCZ;
    bf16_t* HT   = (bf16_t*)(ws + off); off += SCZ;
    float*  sk   = (float*)(ws + off);  off += VSZ;
    float*  sv   = (float*)(ws + off);  off += VSZ;
    float*  gk   = (float*)(ws + off);  off += C_ * 4;
    float*  va   = (float*)(ws + off);  off += C_ * 4;
    float*  s1p  = (float*)(ws + off);  off += 64;
    float*  s2   = (float*)(ws + off);  off += 64;
    float*  uu   = (float*)(ws + off);  off += VSZ;
    float*  vbr  = (float*)(ws + off);  off += VSZ;
    float*  hb   = (float*)(ws + off);  off += VSZ;

    const dim3 blk(256);

    // 1. weights: WqT, WkT, Wv cast + s1
    weights_kernel<<<dim3(193), blk, 0, stream>>>(
        wq, wk, wv, bq, bk, WqTb, WkTb, Wvb, s1p);

    // 2. M = WqT.WkT^T + gk = WkT.bq, va = WqT.bk (parallel row-dots)
    gemm_M_aux<<<dim3(80), blk, 0, stream>>>(WqTb, WkTb, M, bq, bk, gk, va);

    // 3. prep: k,v -> bf16 + row sums; q -> qT + qc (one dispatch)
    prep_kernel<<<dim3(10240), blk, 0, stream>>>(
        k, v, q, kc, vc, qT, qc, sk, sv);

    // 4. D partials (bf16 NT split-K 4, r2-proven 13-16 us)
    gemm_ntK<4><<<dim3(C_ / 128, C_ / 128, B_ * 4), blk, 0, stream>>>(
        kc, vc, Dp, C_, N_, sBN, sBN, sCC);

    // 5. reduce Dp -> D;  u = Wv.sv;  vbraw = M.sk;  s2 = sk.gk + N*s1
    reduce_mv_kernel<<<dim3(1040), blk, 0, stream>>>(
        Dp, D, Wvb, M, sk, sv, gk, s1p, uu, vbr, s2);

    // 6. P1[c2,i] = sum_j Wv[c2,j] D[i,j]
    gemm64_nt<0><<<dim3(8, 8, B_), blk, 0, stream>>>(
        Wvb, D, P1, 0, sCC, sCC,
        nullptr, nullptr, nullptr, nullptr, nullptr, nullptr, nullptr, nullptr);

    // 7. HT = P1.M^T + u (x) va + bv (x) (vbraw + N*va);  h folded (x==0)
    gemm64_nt<3><<<dim3(8, 8, B_), blk, 0, stream>>>(
        P1, M, HT, sCC, 0, sCC, uu, va, bv, vbr, gk, hb, s1p, s2);

    // 8. out = HT.qT^T + h + qc   (fp32, final layout, XCD-swizzled)
    gemm_final<<<dim3(512), blk, 0, stream>>>(HT, qT, out, qc, hb);
}

// Round 13
// 111.189 us; speedup vs baseline: 1.2573x; 1.0677x over previous
//
#include <hip/hip_runtime.h>
#include <hip/hip_bf16.h>
#include <stdint.h>

#define B_ 8
#define C_ 512
#define N_ 2048

typedef __bf16 bf16_t;
typedef bf16_t bf16x8 __attribute__((ext_vector_type(8)));
typedef bf16_t bf16x4 __attribute__((ext_vector_type(4)));
typedef float f32x4 __attribute__((ext_vector_type(4)));

// ---------------------------------------------------------------------------
// prep_all (10433 blocks, one dispatch):
//   0..2047     q transpose-cast: qT[b][n][c] = (bf16)q[b][c][n]  (64x64 tiles)
//   2048..2240  weights: 0..63 WqT, 64..127 WkT, 128..191 Wv cast, 192 s1=bk.bq
//   2241..10432 k/v row cast -> kc/vc bf16 + fp32 row sums sk/sv
// ---------------------------------------------------------------------------
__global__ __launch_bounds__(256) void prep_all_kernel(
    const float* __restrict__ q, const float* __restrict__ kin,
    const float* __restrict__ vin,
    const float* __restrict__ wq, const float* __restrict__ wk,
    const float* __restrict__ wv, const float* __restrict__ bq,
    const float* __restrict__ bk,
    bf16_t* __restrict__ qT, bf16_t* __restrict__ kc, bf16_t* __restrict__ vc,
    bf16_t* __restrict__ WqT, bf16_t* __restrict__ WkT, bf16_t* __restrict__ Wvb,
    float* __restrict__ s1p, float* __restrict__ sk, float* __restrict__ sv)
{
    __shared__ bf16_t tile[64][65];
    __shared__ float red256[256];
    __shared__ float red4[4];
    const int bid = blockIdx.x;
    const int tid = threadIdx.x;

    if (bid < 2048) {
        // ---- q transpose (r1/r9-proven body, qc store removed) ----
        const int b = bid >> 8;
        const int rem = bid & 255;
        const int c0 = (rem >> 5) * 64;
        const int n0 = (rem & 31) * 64;
        const float* src = q + (size_t)b * C_ * N_;
        bf16_t* dT = qT + (size_t)b * N_ * C_;
        const int cx = (tid & 15) * 4, ry = tid >> 4;
#pragma unroll
        for (int r = ry; r < 64; r += 16) {
            float4 f = *(const float4*)&src[(size_t)(c0 + r) * N_ + n0 + cx];
            tile[r][cx + 0] = (bf16_t)f.x; tile[r][cx + 1] = (bf16_t)f.y;
            tile[r][cx + 2] = (bf16_t)f.z; tile[r][cx + 3] = (bf16_t)f.w;
        }
        __syncthreads();
#pragma unroll
        for (int r = ry; r < 64; r += 16) {
            bf16x4 o;
            o[0] = tile[cx + 0][r]; o[1] = tile[cx + 1][r];
            o[2] = tile[cx + 2][r]; o[3] = tile[cx + 3][r];
            *(bf16x4*)&dT[(size_t)(n0 + r) * C_ + c0 + cx] = o;
        }
    } else if (bid < 2241) {
        // ---- weights roles (r11-proven) ----
        const int t = bid - 2048;
        if (t < 128) {
            const float* src = (t < 64) ? wq : wk;
            bf16_t* dst = (t < 64) ? WqT : WkT;
            const int j = t & 63;
            const int i0 = (j & 7) * 64, c0 = (j >> 3) * 64;
            const int cx = (tid & 15) * 4, ry = tid >> 4;
#pragma unroll
            for (int r = ry; r < 64; r += 16) {
                float4 f = *(const float4*)&src[(size_t)(c0 + r) * C_ + i0 + cx];
                tile[r][cx + 0] = (bf16_t)f.x; tile[r][cx + 1] = (bf16_t)f.y;
                tile[r][cx + 2] = (bf16_t)f.z; tile[r][cx + 3] = (bf16_t)f.w;
            }
            __syncthreads();
#pragma unroll
            for (int r = ry; r < 64; r += 16) {
                bf16x4 o;
                o[0] = tile[cx + 0][r]; o[1] = tile[cx + 1][r];
                o[2] = tile[cx + 2][r]; o[3] = tile[cx + 3][r];
                *(bf16x4*)&dst[(size_t)(i0 + r) * C_ + c0 + cx] = o;
            }
        } else if (t < 192) {
            const int j = t - 128;
#pragma unroll
            for (int p = 0; p < 4; ++p) {
                const int i = j * 4096 + p * 1024 + tid * 4;
                float4 f = *(const float4*)(wv + i);
                bf16x4 o;
                o[0] = (bf16_t)f.x; o[1] = (bf16_t)f.y;
                o[2] = (bf16_t)f.z; o[3] = (bf16_t)f.w;
                *(bf16x4*)(Wvb + i) = o;
            }
        } else {
            float p = bk[tid] * bq[tid] + bk[tid + 256] * bq[tid + 256];
            red256[tid] = p;
            __syncthreads();
            for (int s = 128; s > 0; s >>= 1) {
                if (tid < s) red256[tid] += red256[tid + s];
                __syncthreads();
            }
            if (tid == 0) s1p[0] = red256[0];
        }
    } else {
        // ---- k/v row cast + row sums (r8-proven) ----
        const int r = bid - 2241;                  // 0..8191
        const int row = r & 4095;                  // b*C + c
        const int selv = r >> 12;
        const float* src = (selv ? vin : kin) + (size_t)row * N_;
        bf16_t* dst = (selv ? vc : kc) + (size_t)row * N_;
        const int i = tid * 8;
        float4 f0 = *(const float4*)(src + i);
        float4 f1 = *(const float4*)(src + i + 4);
        bf16x8 o;
        o[0] = (bf16_t)f0.x; o[1] = (bf16_t)f0.y; o[2] = (bf16_t)f0.z; o[3] = (bf16_t)f0.w;
        o[4] = (bf16_t)f1.x; o[5] = (bf16_t)f1.y; o[6] = (bf16_t)f1.z; o[7] = (bf16_t)f1.w;
        *(bf16x8*)(dst + i) = o;
        float s = f0.x + f0.y + f0.z + f0.w + f1.x + f1.y + f1.z + f1.w;
#pragma unroll
        for (int d = 1; d < 64; d <<= 1) s += __shfl_xor(s, d, 64);
        if ((tid & 63) == 0) red4[tid >> 6] = s;
        __syncthreads();
        if (tid == 0)
            (selv ? sv : sk)[row] = red4[0] + red4[1] + red4[2] + red4[3];
    }
}

// ---------------------------------------------------------------------------
// dkv_M_kernel (592 blocks, one dispatch):
//   0..511   Dp[b*4+sp][i,j] = sum_{n in sp} kc[i,n]*vc[j,n]  (128-tile split-K,
//            r2-proven body)
//   512..575 M[i',i] = sum_c WqT[i',c]*WkT[i,c]  (64-tile, r8-proven body)
//   576..591 gk = WkT.bq (8 blocks), va = WqT.bk (8 blocks)
// ---------------------------------------------------------------------------
__global__ __launch_bounds__(256, 2) void dkv_M_kernel(
    const bf16_t* __restrict__ kc, const bf16_t* __restrict__ vc,
    bf16_t* __restrict__ Dp,
    const bf16_t* __restrict__ WqT, const bf16_t* __restrict__ WkT,
    bf16_t* __restrict__ M, const float* __restrict__ bq,
    const float* __restrict__ bk, float* __restrict__ gk,
    float* __restrict__ va)
{
    __shared__ __align__(16) bf16_t As[128 * 64];
    __shared__ __align__(16) bf16_t Bs[128 * 64];
    const int f = blockIdx.x;
    const int tid = threadIdx.x, lane = tid & 63, wave = tid >> 6;
    const int wr = wave >> 1, wc = wave & 1;
    const size_t sCC = (size_t)C_ * C_;
    const size_t sBN = (size_t)N_ * C_;

    if (f < 512) {
        const int zz = f >> 4;                     // bz*4+sp
        const int bz = zz >> 2, sp = zz & 3;
        const int t4 = f & 15;
        const int m0 = (t4 >> 2) * 128, n0 = (t4 & 3) * 128;
        const int kbeg = sp * 512;
        const bf16_t* Ab = kc + (size_t)bz * sBN;
        const bf16_t* Bb = vc + (size_t)bz * sBN;

        f32x4 acc[4][4];
#pragma unroll
        for (int i = 0; i < 4; ++i)
#pragma unroll
            for (int j = 0; j < 4; ++j) acc[i][j] = 0.f;

        const int srow = tid >> 3;
        const int scol = ((tid & 7) ^ (srow & 7)) * 8;
        const int ldso = tid * 16;

        for (int t = 0; t < 8; ++t) {
            const bf16_t* ga = Ab + (size_t)(m0 + srow) * N_ + kbeg + t * 64 + scol;
            const bf16_t* gb = Bb + (size_t)(n0 + srow) * N_ + kbeg + t * 64 + scol;
#pragma unroll
            for (int p = 0; p < 4; ++p)
                __builtin_amdgcn_global_load_lds(
                    (const __attribute__((address_space(1))) void*)(ga + (size_t)p * 32 * N_),
                    (__attribute__((address_space(3))) void*)((char*)As + ldso + p * 4096),
                    16, 0, 0);
#pragma unroll
            for (int p = 0; p < 4; ++p)
                __builtin_amdgcn_global_load_lds(
                    (const __attribute__((address_space(1))) void*)(gb + (size_t)p * 32 * N_),
                    (__attribute__((address_space(3))) void*)((char*)Bs + ldso + p * 4096),
                    16, 0, 0);
            __syncthreads();

#pragma unroll
            for (int kk = 0; kk < 64; kk += 32) {
                bf16x8 af[4], bfr[4];
                const int kcol = kk + (lane >> 4) * 8;
                const int kcn = kcol >> 3;
#pragma unroll
                for (int m = 0; m < 4; ++m) {
                    const int r = wr * 64 + (lane & 15) + m * 16;
                    af[m] = *(const bf16x8*)((const char*)As + r * 128 +
                                             ((kcn ^ (r & 7)) << 4));
                }
#pragma unroll
                for (int n = 0; n < 4; ++n) {
                    const int r = wc * 64 + (lane & 15) + n * 16;
                    bfr[n] = *(const bf16x8*)((const char*)Bs + r * 128 +
                                              ((kcn ^ (r & 7)) << 4));
                }
#pragma unroll
                for (int m = 0; m < 4; ++m)
#pragma unroll
                    for (int n = 0; n < 4; ++n)
                        acc[m][n] = __builtin_amdgcn_mfma_f32_16x16x32_bf16(
                            af[m], bfr[n], acc[m][n], 0, 0, 0);
            }
            __syncthreads();
        }

        const int rj = (lane >> 4) * 4;
        const int cc = lane & 15;
#pragma unroll
        for (int m = 0; m < 4; ++m)
#pragma unroll
            for (int n = 0; n < 4; ++n) {
                const int col = n0 + wc * 64 + n * 16 + cc;
                f32x4 vv = acc[m][n];
#pragma unroll
                for (int j = 0; j < 4; ++j) {
                    const int row = m0 + wr * 64 + m * 16 + rj + j;
                    Dp[(size_t)zz * sCC + (size_t)row * C_ + col] = (bf16_t)vv[j];
                }
            }
    } else if (f < 576) {
        const int g = f - 512;
        const int m0 = (g >> 3) * 64, n0 = (g & 7) * 64;
        f32x4 acc[2][2];
#pragma unroll
        for (int i = 0; i < 2; ++i)
#pragma unroll
            for (int j = 0; j < 2; ++j) acc[i][j] = 0.f;
        const int srow = tid >> 3;
        const int scol = ((tid & 7) ^ (srow & 7)) * 8;
        const int ldso = tid * 16;
        for (int t = 0; t < 8; ++t) {
            const bf16_t* ga = WqT + (size_t)(m0 + srow) * C_ + t * 64 + scol;
            const bf16_t* gb = WkT + (size_t)(n0 + srow) * C_ + t * 64 + scol;
#pragma unroll
            for (int p = 0; p < 2; ++p)
                __builtin_amdgcn_global_load_lds(
                    (const __attribute__((address_space(1))) void*)(ga + (size_t)p * 32 * C_),
                    (__attribute__((address_space(3))) void*)((char*)As + ldso + p * 4096),
                    16, 0, 0);
#pragma unroll
            for (int p = 0; p < 2; ++p)
                __builtin_amdgcn_global_load_lds(
                    (const __attribute__((address_space(1))) void*)(gb + (size_t)p * 32 * C_),
                    (__attribute__((address_space(3))) void*)((char*)Bs + ldso + p * 4096),
                    16, 0, 0);
            __syncthreads();
#pragma unroll
            for (int kk = 0; kk < 64; kk += 32) {
                bf16x8 af[2], bfr[2];
                const int kcol = kk + (lane >> 4) * 8;
                const int kcn = kcol >> 3;
#pragma unroll
                for (int m = 0; m < 2; ++m) {
                    const int r = wr * 32 + (lane & 15) + m * 16;
                    af[m] = *(const bf16x8*)((const char*)As + r * 128 +
                                             ((kcn ^ (r & 7)) << 4));
                }
#pragma unroll
                for (int n = 0; n < 2; ++n) {
                    const int r = wc * 32 + (lane & 15) + n * 16;
                    bfr[n] = *(const bf16x8*)((const char*)Bs + r * 128 +
                                              ((kcn ^ (r & 7)) << 4));
                }
#pragma unroll
                for (int m = 0; m < 2; ++m)
#pragma unroll
                    for (int n = 0; n < 2; ++n)
                        acc[m][n] = __builtin_amdgcn_mfma_f32_16x16x32_bf16(
                            af[m], bfr[n], acc[m][n], 0, 0, 0);
            }
            __syncthreads();
        }
        const int rj = (lane >> 4) * 4;
        const int cc = lane & 15;
#pragma unroll
        for (int m = 0; m < 2; ++m)
#pragma unroll
            for (int n = 0; n < 2; ++n) {
                const int col = n0 + wc * 32 + n * 16 + cc;
                f32x4 vv = acc[m][n];
#pragma unroll
                for (int j = 0; j < 4; ++j) {
                    const int row = m0 + wr * 32 + m * 16 + rj + j;
                    M[(size_t)row * C_ + col] = (bf16_t)vv[j];
                }
            }
    } else {
        const int j = f - 576;                     // 0..15
        const bf16_t* W = (j < 8) ? WkT : WqT;
        const float* bb = (j < 8) ? bq : bk;
        float* out = (j < 8) ? gk : va;
        const int row = (j & 7) * 64 + (tid >> 2);
        const int c0 = (tid & 3) * 128;
        const bf16_t* rp = W + (size_t)row * C_ + c0;
        float acc = 0.f;
#pragma unroll
        for (int e = 0; e < 128; e += 8) {
            bf16x8 vv = *(const bf16x8*)(rp + e);
#pragma unroll
            for (int x = 0; x < 8; ++x) acc += (float)vv[x] * bb[c0 + e + x];
        }
        acc += __shfl_xor(acc, 1, 64);
        acc += __shfl_xor(acc, 2, 64);
        if ((tid & 3) == 0) out[row] = acc;
    }
}

// ---------------------------------------------------------------------------
// p1_fused (528 blocks):
//   0..511   P1[bz][c2,i] = sum_{sp,j} Wv[c2,j] * Dp[bz*4+sp][i,j]
//            (64-tile, K=2048 over 4 Dp slices; fp32 accumulate — reduce fused)
//   512..519 u[b] = Wv . sv[b]
//   520..527 vbraw[b] = M . sk[b];  s2[b] = sk[b].gk + N*s1
// ---------------------------------------------------------------------------
__global__ __launch_bounds__(256) void p1_fused_kernel(
    const bf16_t* __restrict__ Wvb, const bf16_t* __restrict__ Dp,
    bf16_t* __restrict__ P1, const bf16_t* __restrict__ M,
    const float* __restrict__ sk, const float* __restrict__ sv,
    const float* __restrict__ gk, const float* __restrict__ s1p,
    float* __restrict__ u, float* __restrict__ vbraw, float* __restrict__ s2)
{
    __shared__ __align__(16) bf16_t As[64 * 64];
    __shared__ __align__(16) bf16_t Bs[64 * 64];
    __shared__ float svec[C_];
    __shared__ float red[256];
    const int f = blockIdx.x;
    const int tid = threadIdx.x, lane = tid & 63, wave = tid >> 6;
    const int wr = wave >> 1, wc = wave & 1;
    const size_t sCC = (size_t)C_ * C_;

    if (f < 512) {
        const int bz = f >> 6;
        const int m0 = ((f >> 3) & 7) * 64, n0 = (f & 7) * 64;
        f32x4 acc[2][2];
#pragma unroll
        for (int i = 0; i < 2; ++i)
#pragma unroll
            for (int j = 0; j < 2; ++j) acc[i][j] = 0.f;
        const int srow = tid >> 3;
        const int scol = ((tid & 7) ^ (srow & 7)) * 8;
        const int ldso = tid * 16;

        for (int sp = 0; sp < 4; ++sp) {
            const bf16_t* Bb = Dp + (size_t)(bz * 4 + sp) * sCC;
            for (int t = 0; t < 8; ++t) {
                const bf16_t* ga = Wvb + (size_t)(m0 + srow) * C_ + t * 64 + scol;
                const bf16_t* gb = Bb + (size_t)(n0 + srow) * C_ + t * 64 + scol;
#pragma unroll
                for (int p = 0; p < 2; ++p)
                    __builtin_amdgcn_global_load_lds(
                        (const __attribute__((address_space(1))) void*)(ga + (size_t)p * 32 * C_),
                        (__attribute__((address_space(3))) void*)((char*)As + ldso + p * 4096),
                        16, 0, 0);
#pragma unroll
                for (int p = 0; p < 2; ++p)
                    __builtin_amdgcn_global_load_lds(
                        (const __attribute__((address_space(1))) void*)(gb + (size_t)p * 32 * C_),
                        (__attribute__((address_space(3))) void*)((char*)Bs + ldso + p * 4096),
                        16, 0, 0);
                __syncthreads();
#pragma unroll
                for (int kk = 0; kk < 64; kk += 32) {
                    bf16x8 af[2], bfr[2];
                    const int kcol = kk + (lane >> 4) * 8;
                    const int kcn = kcol >> 3;
#pragma unroll
                    for (int m = 0; m < 2; ++m) {
                        const int r = wr * 32 + (lane & 15) + m * 16;
                        af[m] = *(const bf16x8*)((const char*)As + r * 128 +
                                                 ((kcn ^ (r & 7)) << 4));
                    }
#pragma unroll
                    for (int n = 0; n < 2; ++n) {
                        const int r = wc * 32 + (lane & 15) + n * 16;
                        bfr[n] = *(const bf16x8*)((const char*)Bs + r * 128 +
                                                  ((kcn ^ (r & 7)) << 4));
                    }
#pragma unroll
                    for (int m = 0; m < 2; ++m)
#pragma unroll
                        for (int n = 0; n < 2; ++n)
                            acc[m][n] = __builtin_amdgcn_mfma_f32_16x16x32_bf16(
                                af[m], bfr[n], acc[m][n], 0, 0, 0);
                }
                __syncthreads();
            }
        }
        const int rj = (lane >> 4) * 4;
        const int cc = lane & 15;
#pragma unroll
        for (int m = 0; m < 2; ++m)
#pragma unroll
            for (int n = 0; n < 2; ++n) {
                const int col = n0 + wc * 32 + n * 16 + cc;
                f32x4 vv = acc[m][n];
#pragma unroll
                for (int j = 0; j < 4; ++j) {
                    const int row = m0 + wr * 32 + m * 16 + rj + j;
                    P1[(size_t)bz * sCC + (size_t)row * C_ + col] = (bf16_t)vv[j];
                }
            }
    } else if (f < 520) {
        const int b = f - 512;
        const float* s4 = sv + (size_t)b * C_;
        svec[tid * 2] = s4[tid * 2];
        svec[tid * 2 + 1] = s4[tid * 2 + 1];
        __syncthreads();
        const int c = tid * 2;
#pragma unroll
        for (int rr = 0; rr < 2; ++rr) {
            const bf16_t* row = Wvb + (size_t)(c + rr) * C_;
            float acc = 0.f;
            for (int j = 0; j < C_; j += 8) {
                bf16x8 vv = *(const bf16x8*)(row + j);
#pragma unroll
                for (int e = 0; e < 8; ++e) acc += (float)vv[e] * svec[j + e];
            }
            u[b * C_ + c + rr] = acc;
        }
    } else {
        const int b = f - 520;
        const float* s4 = sk + (size_t)b * C_;
        svec[tid * 2] = s4[tid * 2];
        svec[tid * 2 + 1] = s4[tid * 2 + 1];
        __syncthreads();
        const int c = tid * 2;
#pragma unroll
        for (int rr = 0; rr < 2; ++rr) {
            const bf16_t* row = M + (size_t)(c + rr) * C_;
            float acc = 0.f;
            for (int j = 0; j < C_; j += 8) {
                bf16x8 vv = *(const bf16x8*)(row + j);
#pragma unroll
                for (int e = 0; e < 8; ++e) acc += (float)vv[e] * svec[j + e];
            }
            vbraw[b * C_ + c + rr] = acc;
        }
        float p = svec[tid] * gk[tid] + svec[tid + 256] * gk[tid + 256];
        red[tid] = p;
        __syncthreads();
        for (int s = 128; s > 0; s >>= 1) {
            if (tid < s) red[tid] += red[tid + s];
            __syncthreads();
        }
        if (tid == 0) s2[b] = red[0] + 2048.0f * s1p[0];
    }
}

// ---------------------------------------------------------------------------
// HT GEMM (64-tile, K=512): HT = P1.M^T + u (x) va + bv (x) (vbraw + N*va);
// x==0 blocks also compute h (r11-verified fold).
// ---------------------------------------------------------------------------
__global__ __launch_bounds__(256) void gemm_ht(
    const bf16_t* __restrict__ A, const bf16_t* __restrict__ Bm,
    bf16_t* __restrict__ Cout,
    const float* __restrict__ e0, const float* __restrict__ e1,
    const float* __restrict__ e2, const float* __restrict__ e3,
    const float* __restrict__ bqv, float* __restrict__ hout,
    const float* __restrict__ s1p, const float* __restrict__ s2p)
{
    __shared__ __align__(16) bf16_t As[64 * 64];
    __shared__ __align__(16) bf16_t Bs[64 * 64];

    const int tid = threadIdx.x, lane = tid & 63, wave = tid >> 6;
    const int wr = wave >> 1, wc = wave & 1;
    const int bz = blockIdx.z;
    const int m0 = blockIdx.y * 64, n0 = blockIdx.x * 64;
    const size_t sCC = (size_t)C_ * C_;

    const bf16_t* Ab = A + (size_t)bz * sCC;

    f32x4 acc[2][2];
#pragma unroll
    for (int i = 0; i < 2; ++i)
#pragma unroll
        for (int j = 0; j < 2; ++j) acc[i][j] = 0.f;

    const int srow = tid >> 3;
    const int scol = ((tid & 7) ^ (srow & 7)) * 8;
    const int ldso = tid * 16;

    float hacc = 0.f;
    const bool doH = (blockIdx.x == 0);

    for (int t = 0; t < 8; ++t) {
        const bf16_t* ga = Ab + (size_t)(m0 + srow) * C_ + t * 64 + scol;
        const bf16_t* gb = Bm + (size_t)(n0 + srow) * C_ + t * 64 + scol;
#pragma unroll
        for (int p = 0; p < 2; ++p)
            __builtin_amdgcn_global_load_lds(
                (const __attribute__((address_space(1))) void*)(ga + (size_t)p * 32 * C_),
                (__attribute__((address_space(3))) void*)((char*)As + ldso + p * 4096),
                16, 0, 0);
#pragma unroll
        for (int p = 0; p < 2; ++p)
            __builtin_amdgcn_global_load_lds(
                (const __attribute__((address_space(1))) void*)(gb + (size_t)p * 32 * C_),
                (__attribute__((address_space(3))) void*)((char*)Bs + ldso + p * 4096),
                16, 0, 0);
        __syncthreads();

#pragma unroll
        for (int kk = 0; kk < 64; kk += 32) {
            bf16x8 af[2], bfr[2];
            const int kcol = kk + (lane >> 4) * 8;
            const int kcn = kcol >> 3;
#pragma unroll
            for (int m = 0; m < 2; ++m) {
                const int r = wr * 32 + (lane & 15) + m * 16;
                af[m] = *(const bf16x8*)((const char*)As + r * 128 +
                                         ((kcn ^ (r & 7)) << 4));
            }
#pragma unroll
            for (int n = 0; n < 2; ++n) {
                const int r = wc * 32 + (lane & 15) + n * 16;
                bfr[n] = *(const bf16x8*)((const char*)Bs + r * 128 +
                                          ((kcn ^ (r & 7)) << 4));
            }
#pragma unroll
            for (int m = 0; m < 2; ++m)
#pragma unroll
                for (int n = 0; n < 2; ++n)
                    acc[m][n] = __builtin_amdgcn_mfma_f32_16x16x32_bf16(
                        af[m], bfr[n], acc[m][n], 0, 0, 0);
        }
        if (doH) {
            const int rr = tid >> 2, qq = tid & 3;
#pragma unroll
            for (int uq = 0; uq < 2; ++uq) {
                const int c = qq * 2 + uq;
                bf16x8 av = *(const bf16x8*)((const char*)As + rr * 128 +
                                             ((c ^ (rr & 7)) << 4));
                const float* bp = bqv + t * 64 + c * 8;
#pragma unroll
                for (int e = 0; e < 8; ++e) hacc += (float)av[e] * bp[e];
            }
        }
        __syncthreads();
    }

    const int rj = (lane >> 4) * 4;
    const int cc = lane & 15;
#pragma unroll
    for (int m = 0; m < 2; ++m) {
#pragma unroll
        for (int n = 0; n < 2; ++n) {
            const int col = n0 + wc * 32 + n * 16 + cc;
            f32x4 vv = acc[m][n];
#pragma unroll
            for (int j = 0; j < 4; ++j) {
                const int row = m0 + wr * 32 + m * 16 + rj + j;
                float val = vv[j] + e0[bz * C_ + row] * e1[col] +
                            e2[row] * (e3[bz * C_ + col] + 2048.0f * e1[col]);
                Cout[(size_t)bz * sCC + (size_t)row * C_ + col] = (bf16_t)val;
            }
        }
    }
    if (doH) {
        hacc += __shfl_xor(hacc, 1, 64);
        hacc += __shfl_xor(hacc, 2, 64);
        if ((tid & 3) == 0) {
            const int row = m0 + (tid >> 2);
            hout[bz * C_ + row] = hacc + e0[bz * C_ + row] * s1p[0] +
                                  e2[row] * s2p[bz];
        }
    }
}

// ---------------------------------------------------------------------------
// Final GEMM: out[c,n] = sum_i HT[c,i]*qT[n,i] + h[b][c] + q[c,n] (fp32 resid).
// 1-D XCD-swizzled grid (512).
// ---------------------------------------------------------------------------
__global__ __launch_bounds__(256) void gemm_final(
    const bf16_t* __restrict__ A, const bf16_t* __restrict__ Bm,
    float* __restrict__ Cout, const float* __restrict__ qres,
    const float* __restrict__ hvec)
{
    __shared__ __align__(16) bf16_t As[128 * 64];
    __shared__ __align__(16) bf16_t Bs[128 * 64];

    const int f = blockIdx.x;
    const int xcd = f & 7, sl = f >> 3;
    const int g = xcd + 8 * (sl >> 2);
    const int m0 = (sl & 3) * 128;
    const int bz = g >> 4;
    const int n0 = (g & 15) * 128;
    const int K = C_;

    const int tid = threadIdx.x, lane = tid & 63, wave = tid >> 6;
    const int wr = wave >> 1, wc = wave & 1;

    const bf16_t* Ab = A + (size_t)bz * ((size_t)C_ * C_);
    const bf16_t* Bb = Bm + (size_t)bz * ((size_t)N_ * C_);

    f32x4 acc[4][4];
#pragma unroll
    for (int i = 0; i < 4; ++i)
#pragma unroll
        for (int j = 0; j < 4; ++j) acc[i][j] = 0.f;

    const int srow = tid >> 3;
    const int scol = ((tid & 7) ^ (srow & 7)) * 8;
    const int ldso = tid * 16;

    for (int t = 0; t < 8; ++t) {
        const bf16_t* ga = Ab + (size_t)(m0 + srow) * K + t * 64 + scol;
        const bf16_t* gb = Bb + (size_t)(n0 + srow) * K + t * 64 + scol;
#pragma unroll
        for (int p = 0; p < 4; ++p)
            __builtin_amdgcn_global_load_lds(
                (const __attribute__((address_space(1))) void*)(ga + (size_t)p * 32 * K),
                (__attribute__((address_space(3))) void*)((char*)As + ldso + p * 4096),
                16, 0, 0);
#pragma unroll
        for (int p = 0; p < 4; ++p)
            __builtin_amdgcn_global_load_lds(
                (const __attribute__((address_space(1))) void*)(gb + (size_t)p * 32 * K),
                (__attribute__((address_space(3))) void*)((char*)Bs + ldso + p * 4096),
                16, 0, 0);
        __syncthreads();

#pragma unroll
        for (int kk = 0; kk < 64; kk += 32) {
            bf16x8 af[4], bfr[4];
            const int kcol = kk + (lane >> 4) * 8;
            const int kcn = kcol >> 3;
#pragma unroll
            for (int m = 0; m < 4; ++m) {
                const int r = wr * 64 + (lane & 15) + m * 16;
                af[m] = *(const bf16x8*)((const char*)As + r * 128 +
                                         ((kcn ^ (r & 7)) << 4));
            }
#pragma unroll
            for (int n = 0; n < 4; ++n) {
                const int r = wc * 64 + (lane & 15) + n * 16;
                bfr[n] = *(const bf16x8*)((const char*)Bs + r * 128 +
                                          ((kcn ^ (r & 7)) << 4));
            }
#pragma unroll
            for (int m = 0; m < 4; ++m)
#pragma unroll
                for (int n = 0; n < 4; ++n)
                    acc[m][n] = __builtin_amdgcn_mfma_f32_16x16x32_bf16(
                        af[m], bfr[n], acc[m][n], 0, 0, 0);
        }
        __syncthreads();
    }

    const int rj = (lane >> 4) * 4;
    const int cc = lane & 15;
    const size_t ob = (size_t)bz * ((size_t)C_ * N_);
#pragma unroll
    for (int m = 0; m < 4; ++m) {
#pragma unroll
        for (int n = 0; n < 4; ++n) {
            const int col = n0 + wc * 64 + n * 16 + cc;
            f32x4 vv = acc[m][n];
#pragma unroll
            for (int j = 0; j < 4; ++j) {
                const int row = m0 + wr * 64 + m * 16 + rj + j;
                const size_t o = ob + (size_t)row * N_ + col;
                Cout[o] = vv[j] + hvec[bz * C_ + row] + qres[o];
            }
        }
    }
}

// ---------------------------------------------------------------------------
extern "C" void kernel_launch(void* const* d_in, const int* in_sizes, int n_in,
                              void* d_out, int out_size, void* d_ws, size_t ws_size,
                              hipStream_t stream)
{
    (void)in_sizes; (void)n_in; (void)out_size; (void)ws_size;
    const float* q  = (const float*)d_in[0];
    const float* k  = (const float*)d_in[1];
    const float* v  = (const float*)d_in[2];
    const float* wq = (const float*)d_in[3];
    const float* bq = (const float*)d_in[4];
    const float* wk = (const float*)d_in[5];
    const float* bk = (const float*)d_in[6];
    const float* wv = (const float*)d_in[7];
    const float* bv = (const float*)d_in[8];
    float* out = (float*)d_out;

    char* ws = (char*)d_ws;
    const size_t WSZ = (size_t)C_ * C_ * 2;            // 512 KB
    const size_t TSZ = (size_t)B_ * N_ * C_ * 2;       // 16.78 MB
    const size_t SCZ = (size_t)B_ * C_ * C_ * 2;       // 4.19 MB
    const size_t VSZ = (size_t)B_ * C_ * 4;            // 16 KB
    const size_t sCC = (size_t)C_ * C_;
    size_t off = 0;
    bf16_t* WqTb = (bf16_t*)(ws + off); off += WSZ;
    bf16_t* WkTb = (bf16_t*)(ws + off); off += WSZ;
    bf16_t* Wvb  = (bf16_t*)(ws + off); off += WSZ;
    bf16_t* M    = (bf16_t*)(ws + off); off += WSZ;
    bf16_t* qT   = (bf16_t*)(ws + off); off += TSZ;
    bf16_t* kc   = (bf16_t*)(ws + off); off += TSZ;
    bf16_t* vc   = (bf16_t*)(ws + off); off += TSZ;
    bf16_t* Dp   = (bf16_t*)(ws + off); off += TSZ;    // 32 x sCC partials
    bf16_t* P1   = (bf16_t*)(ws + off); off += SCZ;
    bf16_t* HT   = (bf16_t*)(ws + off); off += SCZ;
    float*  sk   = (float*)(ws + off);  off += VSZ;
    float*  sv   = (float*)(ws + off);  off += VSZ;
    float*  gk   = (float*)(ws + off);  off += C_ * 4;
    float*  va   = (float*)(ws + off);  off += C_ * 4;
    float*  s1p  = (float*)(ws + off);  off += 64;
    float*  s2   = (float*)(ws + off);  off += 64;
    float*  uu   = (float*)(ws + off);  off += VSZ;
    float*  vbr  = (float*)(ws + off);  off += VSZ;
    float*  hb   = (float*)(ws + off);  off += VSZ;

    const dim3 blk(256);

    // 1. prep_all: q->qT, weights (WqT/WkT/Wv/s1), k/v cast + sums
    prep_all_kernel<<<dim3(10433), blk, 0, stream>>>(
        q, k, v, wq, wk, wv, bq, bk, qT, kc, vc, WqTb, WkTb, Wvb, s1p, sk, sv);

    // 2. Dp split-K GEMM + M = WqT.WkT^T + gk/va row-dots (one dispatch)
    dkv_M_kernel<<<dim3(592), blk, 0, stream>>>(
        kc, vc, Dp, WqTb, WkTb, M, bq, bk, gk, va);

    // 3. P1 = Wv . (sum_sp Dp)^T (K=2048, reduce fused) + u/vbraw/s2
    p1_fused_kernel<<<dim3(528), blk, 0, stream>>>(
        Wvb, Dp, P1, M, sk, sv, gk, s1p, uu, vbr, s2);

    // 4. HT = P1.M^T + rank-1; h folded into x==0 blocks
    gemm_ht<<<dim3(8, 8, B_), blk, 0, stream>>>(
        P1, M, HT, uu, va, bv, vbr, gk, hb, s1p, s2);

    // 5. out = HT.qT^T + h + q  (fp32 residual read directly)
    gemm_final<<<dim3(512), blk, 0, stream>>>(HT, qT, out, q, hb);
}